// Round 5
// baseline (69.312 us; speedup 1.0000x reference)
//
#include <hip/hip_runtime.h>
#include <math.h>

#define NQ 4
#define NL 6
#define DIM 16
#define BLOCK 256

typedef float v2 __attribute__((ext_vector_type(2)));

// R5: FUSE THE CIRCUIT. The 24 Rot gates + CNOTs are batch-uniform, so the
// whole entangling block is one fixed 16x16 complex unitary W.
//   Phase A (threads 0..15 of every block, redundant per block): build
//     column j of W by applying the scalar gate sequence to basis e_j.
//     ~4 us, fully overlapped across blocks/CUs.
//   Phase B (all threads, 1 thread = 1 sample): y = W * psi(x), probs,
//     <Z>. psi_c = (-i)^popcount(c) * mag_c is purely real OR imag, so each
//     (col, row-pair) is 2 v_pk_fma_f32 -> 256 packed FMAs total.
// Per-thread dynamic work: ~1600 ops (R3) -> ~450 ops.
// R4 lane-split was neutral => kernel is issue/serial-work bound, not
// latency-bound; so remove work, don't reschedule it.
__global__ __launch_bounds__(BLOCK) void vqc_kernel(
    const float* __restrict__ inputs,   // [B, 4]
    const float* __restrict__ rot,      // [6, 4, 3]
    float* __restrict__ out,            // [B, 4]
    int batch)
{
    __shared__ float U[NL * NQ][8];   // u00r,u00i,u01r,u01i,u10r,u10i,u11r,u11i
    __shared__ v2 WR[DIM][8];         // WR[c][rp] = {Wr[2rp][c], Wr[2rp+1][c]}
    __shared__ v2 WI[DIM][8];

    const int tid = threadIdx.x;
    if (tid < NL * NQ) {
        float phi = rot[tid * 3 + 0];
        float theta = rot[tid * 3 + 1];
        float omega = rot[tid * 3 + 2];
        float st, ct;
        __sincosf(0.5f * theta, &st, &ct);
        float a = 0.5f * (phi + omega);   // ep = exp(-i a) = ca - i sa
        float b = 0.5f * (phi - omega);   // em = exp(+i b) = cb + i sb
        float sa, ca, sb, cb;
        __sincosf(a, &sa, &ca);
        __sincosf(b, &sb, &cb);
        U[tid][0] = ca * ct;   // u00 = ep*ct
        U[tid][1] = -sa * ct;
        U[tid][2] = -cb * st;  // u01 = -em*st
        U[tid][3] = -sb * st;
        U[tid][4] = cb * st;   // u10 = conj(em)*st
        U[tid][5] = -sb * st;
        U[tid][6] = ca * ct;   // u11 = conj(ep)*ct
        U[tid][7] = sa * ct;
    }
    __syncthreads();

    // ---- Phase A: thread j (<16) builds column j of W ----
    if (tid < DIM) {
        float ar[DIM], ai[DIM];
#pragma unroll
        for (int i = 0; i < DIM; ++i) { ar[i] = (i == tid) ? 1.f : 0.f; ai[i] = 0.f; }
#pragma unroll 1
        for (int half = 0; half < 2; ++half) {
            const int ubase = half * (3 * NQ);
#pragma unroll
            for (int li = 0; li < 3; ++li) {
#pragma unroll
                for (int q = 0; q < NQ; ++q) {
                    const float* u = U[ubase + li * NQ + q];
                    const float u00r = u[0], u00i = u[1], u01r = u[2], u01i = u[3];
                    const float u10r = u[4], u10i = u[5], u11r = u[6], u11i = u[7];
                    const int m = 1 << (3 - q);
#pragma unroll
                    for (int i = 0; i < DIM; ++i) {
                        if (!(i & m)) {
                            const int j = i | m;
                            const float a0r = ar[i], a0i = ai[i];
                            const float a1r = ar[j], a1i = ai[j];
                            ar[i] = u00r * a0r - u00i * a0i + u01r * a1r - u01i * a1i;
                            ai[i] = u00r * a0i + u00i * a0r + u01r * a1i + u01i * a1r;
                            ar[j] = u10r * a0r - u10i * a0i + u11r * a1r - u11i * a1i;
                            ai[j] = u10r * a0i + u10i * a0r + u11r * a1i + u11i * a1r;
                        }
                    }
                }
                const int r = li + 1;
#pragma unroll
                for (int q = 0; q < NQ; ++q) {
                    const int t = (q + r) & 3;
                    const int cm = 1 << (3 - q);
                    const int tm = 1 << (3 - t);
#pragma unroll
                    for (int i = 0; i < DIM; ++i) {
                        if ((i & cm) && !(i & tm)) {
                            const int j = i | tm;
                            float tr = ar[i]; ar[i] = ar[j]; ar[j] = tr;
                            float ti = ai[i]; ai[i] = ai[j]; ai[j] = ti;
                        }
                    }
                }
            }
        }
#pragma unroll
        for (int rp = 0; rp < 8; ++rp) {
            WR[tid][rp] = (v2){ar[2 * rp], ar[2 * rp + 1]};
            WI[tid][rp] = (v2){ai[2 * rp], ai[2 * rp + 1]};
        }
    }
    __syncthreads();

    // ---- Phase B: one sample per thread ----
    const int b = blockIdx.x * BLOCK + tid;
    if (b >= batch) return;

    const float4 x = ((const float4*)inputs)[b];
    float cc[NQ], ss[NQ];
    __sincosf(0.5f * x.x, &ss[0], &cc[0]);
    __sincosf(0.5f * x.y, &ss[1], &cc[1]);
    __sincosf(0.5f * x.z, &ss[2], &cc[2]);
    __sincosf(0.5f * x.w, &ss[3], &cc[3]);

    // y = W * psi, exploiting psi_c = (-i)^k * m (purely real or imag).
    v2 yr[8], yi[8];
#pragma unroll
    for (int rp = 0; rp < 8; ++rp) { yr[rp] = (v2){0.f, 0.f}; yi[rp] = (v2){0.f, 0.f}; }
#pragma unroll
    for (int cI = 0; cI < DIM; ++cI) {
        const float m = (((cI >> 3) & 1) ? ss[0] : cc[0])
                      * (((cI >> 2) & 1) ? ss[1] : cc[1])
                      * (((cI >> 1) & 1) ? ss[2] : cc[2])
                      * (((cI >> 0) & 1) ? ss[3] : cc[3]);
        const int k = (((cI >> 3) & 1) + ((cI >> 2) & 1) + ((cI >> 1) & 1) + (cI & 1)) & 3;
#pragma unroll
        for (int rp = 0; rp < 8; ++rp) {
            const v2 wr = WR[cI][rp], wi = WI[cI][rp];
            // psi = (-i)^k * m:
            //  k=0: y += m*(wr + i wi)      k=1: y += m*(wi - i wr)
            //  k=2: y -= m*(wr + i wi)      k=3: y += m*(-wi + i wr)
            if (k == 0)      { yr[rp] += wr * m; yi[rp] += wi * m; }
            else if (k == 1) { yr[rp] += wi * m; yi[rp] -= wr * m; }
            else if (k == 2) { yr[rp] -= wr * m; yi[rp] -= wi * m; }
            else             { yr[rp] -= wi * m; yi[rp] += wr * m; }
        }
    }

    // ---- <Z_q> from probabilities ----
    // row index i = 2*rp + slot; qubit0 = rp bit2, qubit1 = rp bit1,
    // qubit2 = rp bit0, qubit3 = slot.
    v2 a0 = {0.f, 0.f}, a1 = {0.f, 0.f}, a2 = {0.f, 0.f}, a3 = {0.f, 0.f};
    const v2 sgn3 = {1.f, -1.f};
#pragma unroll
    for (int rp = 0; rp < 8; ++rp) {
        const v2 p2 = yr[rp] * yr[rp] + yi[rp] * yi[rp];
        a0 += ((rp >> 2) & 1) ? -p2 : p2;
        a1 += ((rp >> 1) & 1) ? -p2 : p2;
        a2 += (rp & 1) ? -p2 : p2;
        a3 += p2 * sgn3;
    }
    ((float4*)out)[b] = make_float4(a0.x + a0.y, a1.x + a1.y,
                                    a2.x + a2.y, a3.x + a3.y);
}

extern "C" void kernel_launch(void* const* d_in, const int* in_sizes, int n_in,
                              void* d_out, int out_size, void* d_ws, size_t ws_size,
                              hipStream_t stream) {
    const float* inputs = (const float*)d_in[0];   // [B,4] fp32
    const float* rot = (const float*)d_in[1];      // [6,4,3] fp32
    float* out = (float*)d_out;                    // [B,4] fp32
    const int batch = in_sizes[0] / NQ;
    const int grid = (batch + BLOCK - 1) / BLOCK;
    vqc_kernel<<<grid, BLOCK, 0, stream>>>(inputs, rot, out, batch);
}